// Round 1
// baseline (701.222 us; speedup 1.0000x reference)
//
#include <hip/hip_runtime.h>
#include <math.h>

#define HDIM 768
#define HIDD 512
#define HALFD 256
#define NTOK 16384
#define NT 20
#define CHUNKS 128
#define CLEN 128

__device__ __forceinline__ float sigm(float x){ return 1.0f/(1.0f+expf(-x)); }

// ---------------------------------------------------------------------------
// GEMM + gate activation. enc[t][0:256]=h_f, enc[t][256:512]=h_b.
// Note: forget gate is unused by the reference -> only 3 gates (i,g,o) computed.
// Tile: 128 rows x 64 h-cols (=192 gemm cols), 256 threads, 8x12 acc/thread.
// ---------------------------------------------------------------------------
__global__ __launch_bounds__(256) void lstm_gemm_kernel(
    const float* __restrict__ x,
    const float* __restrict__ wf, const float* __restrict__ wb,
    const float* __restrict__ bihf, const float* __restrict__ bhhf,
    const float* __restrict__ bihb, const float* __restrict__ bhhb,
    float* __restrict__ enc)
{
    __shared__ float aT[16][128];
    __shared__ float bT[16][192];
    const int tid = threadIdx.x;
    const int row0 = blockIdx.x * 128;
    const int n0 = blockIdx.y * 64;
    const bool fwd = (n0 < HALFD);
    const float* __restrict__ w   = fwd ? wf   : wb;
    const float* __restrict__ bih = fwd ? bihf : bihb;
    const float* __restrict__ bhh = fwd ? bhhf : bhhb;
    const int jbase = fwd ? n0 : (n0 - HALFD);

    const int ii0 = (tid >> 4) * 8;
    const int jj0 = (tid & 15) * 4;

    float acc[8][12];
    #pragma unroll
    for (int r=0;r<8;++r)
        #pragma unroll
        for (int c=0;c<12;++c) acc[r][c]=0.f;

    for (int k0=0;k0<HDIM;k0+=16){
        #pragma unroll
        for (int g=0; g<2; ++g){
            int l = tid + 256*g;
            int ar = l>>2, ac = (l&3)*4;
            const float4 v = *(const float4*)(x + (size_t)(row0+ar+1)*HDIM + k0 + ac);
            aT[ac+0][ar]=v.x; aT[ac+1][ar]=v.y; aT[ac+2][ar]=v.z; aT[ac+3][ar]=v.w;
        }
        #pragma unroll
        for (int g=0; g<3; ++g){
            int l = tid + 256*g;
            int br = l>>2, bc = (l&3)*4;
            int gate = br>>6, jj = br&63;
            int wrow = jbase + jj + ((gate==0)?0:((gate==1)?512:768));
            const float4 v = *(const float4*)(w + (size_t)wrow*HDIM + k0 + bc);
            bT[bc+0][br]=v.x; bT[bc+1][br]=v.y; bT[bc+2][br]=v.z; bT[bc+3][br]=v.w;
        }
        __syncthreads();
        #pragma unroll
        for (int kk=0;kk<16;++kk){
            float4 a0 = *(const float4*)&aT[kk][ii0];
            float4 a1 = *(const float4*)&aT[kk][ii0+4];
            float4 b0 = *(const float4*)&bT[kk][jj0];
            float4 b1 = *(const float4*)&bT[kk][64+jj0];
            float4 b2 = *(const float4*)&bT[kk][128+jj0];
            float av[8]={a0.x,a0.y,a0.z,a0.w,a1.x,a1.y,a1.z,a1.w};
            float bv[12]={b0.x,b0.y,b0.z,b0.w,b1.x,b1.y,b1.z,b1.w,b2.x,b2.y,b2.z,b2.w};
            #pragma unroll
            for (int r=0;r<8;++r)
                #pragma unroll
                for (int c=0;c<12;++c)
                    acc[r][c] = fmaf(av[r], bv[c], acc[r][c]);
        }
        __syncthreads();
    }

    float bi[4],bg[4],bo[4];
    #pragma unroll
    for (int j=0;j<4;++j){
        int jr = jbase + jj0 + j;
        bi[j] = bih[jr]     + bhh[jr];
        bg[j] = bih[jr+512] + bhh[jr+512];
        bo[j] = bih[jr+768] + bhh[jr+768];
    }
    #pragma unroll
    for (int r=0;r<8;++r){
        float hv[4];
        #pragma unroll
        for (int j=0;j<4;++j){
            float iv = acc[r][j]   + bi[j];
            float gv = acc[r][4+j] + bg[j];
            float ov = acc[r][8+j] + bo[j];
            float cv = sigm(iv)*tanhf(gv);
            hv[j] = sigm(ov)*tanhf(cv);
        }
        float4 st = {hv[0],hv[1],hv[2],hv[3]};
        *(float4*)(enc + (size_t)(row0+ii0+r)*HIDD + n0 + jj0) = st;
    }
}

// ---------------------------------------------------------------------------
// feats = enc @ w_tag.T + b_tag   (16384 x 20). 8 rows/block, 32 lanes/row.
// ---------------------------------------------------------------------------
__global__ __launch_bounds__(256) void feats_kernel(
    const float* __restrict__ enc, const float* __restrict__ wtag,
    const float* __restrict__ btag, float* __restrict__ feats)
{
    __shared__ float wt[NT*HIDD];
    const int tid = threadIdx.x;
    for (int idx=tid; idx<NT*HIDD/4; idx+=256)
        ((float4*)wt)[idx] = ((const float4*)wtag)[idx];
    __syncthreads();
    const int row = blockIdx.x*8 + (tid>>5);
    const int lane = tid & 31;
    float ev[16];
    #pragma unroll
    for (int m=0;m<16;++m) ev[m] = enc[(size_t)row*HIDD + lane + 32*m];
    for (int tag=0;tag<NT;++tag){
        float s = 0.f;
        #pragma unroll
        for (int m=0;m<16;++m) s = fmaf(ev[m], wt[tag*HIDD + lane + 32*m], s);
        #pragma unroll
        for (int off=16;off>=1;off>>=1) s += __shfl_xor(s, off, 32);
        if (lane==0) feats[(size_t)row*NT + tag] = s + btag[tag];
    }
}

// ---------------------------------------------------------------------------
// V1: per-chunk max-plus matrix product P_c (20x20). One block per chunk.
// thread (i,j) owns entry P[i][j]; column j only depends on column j.
// ---------------------------------------------------------------------------
__global__ __launch_bounds__(512) void vit_chunkmat(
    const float* __restrict__ feats, const float* __restrict__ trans,
    float* __restrict__ Pall)
{
    __shared__ float fl[CLEN*NT];
    __shared__ float Pb[2][NT*NT];
    const int c = blockIdx.x, tid = threadIdx.x;
    for (int idx=tid; idx<CLEN*NT/4; idx+=512)
        ((float4*)fl)[idx] = ((const float4*)(feats + (size_t)c*CLEN*NT))[idx];
    const bool act = tid < NT*NT;
    const int i = tid/20, j = tid - i*20;
    float tr[NT];
    if (act){
        #pragma unroll
        for (int k=0;k<NT;++k) tr[k] = trans[i*NT+k];
        Pb[0][tid] = (i==j) ? 0.f : -1e30f;   // max-plus identity
    }
    __syncthreads();
    int cur = 0;
    for (int t=0;t<CLEN;++t){
        float m = -3.0e38f;
        if (act){
            #pragma unroll
            for (int k=0;k<NT;++k) m = fmaxf(m, tr[k] + Pb[cur][k*NT+j]);
            m += fl[t*NT+i];
            Pb[cur^1][tid] = m;
        }
        __syncthreads();
        cur ^= 1;
    }
    if (act) Pall[(size_t)c*(NT*NT) + tid] = Pb[cur][tid];
}

// ---------------------------------------------------------------------------
// V2: sequential scan over chunk matrices -> fv at each chunk start; also
// terminal argmax (first-win) -> path_score (d_out[0]) and best state.
// ---------------------------------------------------------------------------
__global__ __launch_bounds__(128) void vit_scan(
    const float* __restrict__ Pall, const float* __restrict__ trans,
    float* __restrict__ fvstart, float* __restrict__ dout, int* __restrict__ bestws)
{
    __shared__ float Pb[NT*NT];
    __shared__ float fv[NT];
    const int tid = threadIdx.x;
    float4 pn = {0.f,0.f,0.f,0.f};
    if (tid<100) pn = ((const float4*)Pall)[tid];
    if (tid<NT) fv[tid] = (tid==18) ? 0.f : -10000.f;   // START=18
    for (int c=0;c<CHUNKS;++c){
        if (tid<100) ((float4*)Pb)[tid] = pn;
        if (tid<100 && c+1<CHUNKS) pn = ((const float4*)(Pall + (size_t)(c+1)*(NT*NT)))[tid];
        __syncthreads();
        if (tid<NT) fvstart[c*NT+tid] = fv[tid];
        float nf = -3.0e38f;
        if (tid<NT){
            #pragma unroll
            for (int j=0;j<NT;++j) nf = fmaxf(nf, Pb[tid*NT+j] + fv[j]);
        }
        __syncthreads();
        if (tid<NT) fv[tid] = nf;
    }
    __syncthreads();
    if (tid==0){
        float best = -3.0e38f; int bidx = 0;
        for (int j=0;j<NT;++j){
            float tv = fv[j] + trans[19*NT+j];   // STOP row = 19
            if (tv > best){ best = tv; bidx = j; }
        }
        dout[0] = best;
        bestws[0] = bidx;
    }
}

// ---------------------------------------------------------------------------
// V3: exact per-step replay within each chunk (reference-identical op order,
// first-index-wins argmax) -> backpointers; also composed reverse map H_c.
// ---------------------------------------------------------------------------
__global__ __launch_bounds__(64) void vit_replay(
    const float* __restrict__ feats, const float* __restrict__ trans,
    const float* __restrict__ fvstart, unsigned int* __restrict__ bpout,
    int* __restrict__ Hout)
{
    __shared__ float fl[CLEN*NT];
    __shared__ float fv[NT];
    __shared__ unsigned char bp[CLEN*NT];
    const int c = blockIdx.x, tid = threadIdx.x;
    for (int idx=tid; idx<CLEN*NT/4; idx+=64)
        ((float4*)fl)[idx] = ((const float4*)(feats + (size_t)c*CLEN*NT))[idx];
    float tr[NT];
    if (tid<NT){
        fv[tid] = fvstart[c*NT+tid];
        #pragma unroll
        for (int k=0;k<NT;++k) tr[k] = trans[tid*NT+k];
    }
    __syncthreads();
    for (int t=0;t<CLEN;++t){
        float best = 0.f; int bj = 0;
        if (tid<NT){
            best = tr[0] + fv[0];
            #pragma unroll
            for (int j=1;j<NT;++j){
                float v = tr[j] + fv[j];
                if (v > best){ best = v; bj = j; }   // strict > == first-win
            }
        }
        __syncthreads();
        if (tid<NT){
            fv[tid] = best + fl[t*NT+tid];
            bp[t*NT+tid] = (unsigned char)bj;
        }
        __syncthreads();
    }
    for (int idx=tid; idx<CLEN*NT/4; idx+=64)
        bpout[(size_t)c*(CLEN*NT/4) + idx] = ((unsigned int*)bp)[idx];
    if (tid<NT){
        int m = tid;
        for (int t=CLEN-1;t>=0;--t) m = bp[t*NT+m];  // H_c = g_cL ∘ ... ∘ g_{cL+L-1}
        Hout[c*NT+tid] = m;
    }
}

// ---------------------------------------------------------------------------
// V4b: sequential chunk-level backtrack through the composed maps H_c.
// echunk[c] = path state at the LAST position of chunk c.
// ---------------------------------------------------------------------------
__global__ __launch_bounds__(64) void bt_scan(
    const int* __restrict__ Hin, const int* __restrict__ bestws,
    int* __restrict__ echunk)
{
    __shared__ int Hl[CHUNKS*NT];
    const int tid = threadIdx.x;
    for (int idx=tid; idx<CHUNKS*NT; idx+=64) Hl[idx] = Hin[idx];
    __syncthreads();
    if (tid==0){
        int e = bestws[0];
        echunk[CHUNKS-1] = e;
        for (int c=CHUNKS-1;c>=1;--c){ e = Hl[c*NT+e]; echunk[c-1] = e; }
    }
}

// ---------------------------------------------------------------------------
// V4c: per-chunk backtrack fill of the output path (floats into d_out[1..]).
// ---------------------------------------------------------------------------
__global__ __launch_bounds__(64) void bt_fill(
    const unsigned int* __restrict__ bpin, const int* __restrict__ echunk,
    float* __restrict__ dout)
{
    __shared__ unsigned char bp[CLEN*NT];
    __shared__ float ob[CLEN];
    const int c = blockIdx.x, tid = threadIdx.x;
    for (int idx=tid; idx<CLEN*NT/4; idx+=64)
        ((unsigned int*)bp)[idx] = bpin[(size_t)c*(CLEN*NT/4) + idx];
    __syncthreads();
    if (tid==0){
        int y = echunk[c];
        for (int t=CLEN-1;t>=0;--t){ ob[t] = (float)y; y = bp[t*NT+y]; }
    }
    __syncthreads();
    for (int idx=tid; idx<CLEN; idx+=64)
        dout[1 + c*CLEN + idx] = ob[idx];
}

// ---------------------------------------------------------------------------
extern "C" void kernel_launch(void* const* d_in, const int* in_sizes, int n_in,
                              void* d_out, int out_size, void* d_ws, size_t ws_size,
                              hipStream_t stream)
{
    const float* x    = (const float*)d_in[0];
    const float* wf   = (const float*)d_in[1];
    const float* bihf = (const float*)d_in[3];
    const float* bhhf = (const float*)d_in[4];
    const float* wb   = (const float*)d_in[5];
    const float* bihb = (const float*)d_in[7];
    const float* bhhb = (const float*)d_in[8];
    const float* wtag = (const float*)d_in[9];
    const float* btag = (const float*)d_in[10];
    const float* trans= (const float*)d_in[11];
    float* out = (float*)d_out;
    float* ws  = (float*)d_ws;

    // workspace layout (floats): ~35.5 MB total
    float* enc   = ws;                        // 16384*512  = 8388608
    float* feats = ws + 8388608;              // 16384*20   = 327680
    float* Pall  = feats + 327680;            // 128*400    = 51200
    float* fvst  = Pall + 51200;              // 128*20     = 2560
    int*   Hmap  = (int*)(fvst + 2560);       // 128*20 ints
    unsigned int* bp = (unsigned int*)(Hmap + 2560);  // 16384*20 bytes = 81920 words
    int*   ech   = (int*)(bp + 81920);        // 128 ints
    int*   best  = ech + CHUNKS;              // 1 int

    lstm_gemm_kernel<<<dim3(128,8), 256, 0, stream>>>(x, wf, wb, bihf, bhhf, bihb, bhhb, enc);
    feats_kernel<<<2048, 256, 0, stream>>>(enc, wtag, btag, feats);
    vit_chunkmat<<<CHUNKS, 512, 0, stream>>>(feats, trans, Pall);
    vit_scan<<<1, 128, 0, stream>>>(Pall, trans, fvst, out, best);
    vit_replay<<<CHUNKS, 64, 0, stream>>>(feats, trans, fvst, bp, Hmap);
    bt_scan<<<1, 64, 0, stream>>>(Hmap, best, ech);
    bt_fill<<<CHUNKS, 64, 0, stream>>>(bp, ech, out);
}

// Round 2
// 506.371 us; speedup vs baseline: 1.3848x; 1.3848x over previous
//
#include <hip/hip_runtime.h>
#include <math.h>

#define HDIM 768
#define HIDD 512
#define NTOK 16384
#define NT 20
#define CHUNKS 128
#define CLEN 128

typedef unsigned short ushort_t;
typedef __attribute__((ext_vector_type(8))) short bf16x8;
typedef __attribute__((ext_vector_type(4))) float f32x4;

__device__ __forceinline__ float sigm(float x){ return 1.0f/(1.0f+expf(-x)); }

__device__ __forceinline__ ushort_t f2bf(float f){
    unsigned int u = __float_as_uint(f);
    unsigned int r = (u + 0x7fffu + ((u >> 16) & 1u)) >> 16;
    return (ushort_t)r;
}
__device__ __forceinline__ float bf2f(ushort_t b){
    return __uint_as_float(((unsigned int)b) << 16);
}

#define GLD16(gp, lp) __builtin_amdgcn_global_load_lds( \
    (const __attribute__((address_space(1))) void*)(gp), \
    (__attribute__((address_space(3))) void*)(lp), 16, 0, 0)

// ---------------------------------------------------------------------------
// convA: x rows 1..16384 -> Ah/Al bf16 split (16384x768, k-contig)
// ---------------------------------------------------------------------------
__global__ __launch_bounds__(256) void convA_kernel(
    const float* __restrict__ x, ushort_t* __restrict__ Ah, ushort_t* __restrict__ Al)
{
    int t = blockIdx.x*256 + threadIdx.x;     // 16384*192 threads
    int row = t / 192, c4 = (t - row*192)*4;
    const float4 v = *(const float4*)(x + (size_t)(row+1)*HDIM + c4);
    float f[4] = {v.x, v.y, v.z, v.w};
    ushort_t h[4], l[4];
    #pragma unroll
    for (int i=0;i<4;++i){
        h[i] = f2bf(f[i]);
        l[i] = f2bf(f[i] - bf2f(h[i]));
    }
    *(ushort4*)(Ah + (size_t)row*HDIM + c4) = make_ushort4(h[0],h[1],h[2],h[3]);
    *(ushort4*)(Al + (size_t)row*HDIM + c4) = make_ushort4(l[0],l[1],l[2],l[3]);
}

// ---------------------------------------------------------------------------
// convB: pack w_ih_{f,b} gates {i,g,o} -> Bh/Bl bf16 (1536x768)
// n = dir*768 + gate*256 + j  ;  w rows: i=j, g=512+j, o=768+j
// ---------------------------------------------------------------------------
__global__ __launch_bounds__(256) void convB_kernel(
    const float* __restrict__ wf, const float* __restrict__ wb,
    ushort_t* __restrict__ Bh, ushort_t* __restrict__ Bl)
{
    int t = blockIdx.x*256 + threadIdx.x;     // 1536*192 threads
    int n = t / 192, c4 = (t - n*192)*4;
    int dir = n / 768, nr = n - dir*768;
    int gate = nr >> 8, j = nr & 255;
    int wrow = j + ((gate==0)?0:((gate==1)?512:768));
    const float* src = dir ? wb : wf;
    const float4 v = *(const float4*)(src + (size_t)wrow*HDIM + c4);
    float f[4] = {v.x, v.y, v.z, v.w};
    ushort_t h[4], l[4];
    #pragma unroll
    for (int i=0;i<4;++i){
        h[i] = f2bf(f[i]);
        l[i] = f2bf(f[i] - bf2f(h[i]));
    }
    *(ushort4*)(Bh + (size_t)n*HDIM + c4) = make_ushort4(h[0],h[1],h[2],h[3]);
    *(ushort4*)(Bl + (size_t)n*HDIM + c4) = make_ushort4(l[0],l[1],l[2],l[3]);
}

// ---------------------------------------------------------------------------
// Fused split-bf16 MFMA GEMM + gate activation.
// Grid 512 blocks: (m-tile 128) x (dir x j-half). Per block: 3 passes (i,g,o),
// each a full K-loop over 4 segments {AhBh, AlBh, AhBl, AlBl} x 12 BK=64 steps.
// LDS tiles [m][k8] with k8 XOR (m&7) swizzle: coalesced global_load_lds +
// conflict-free(2-way) ds_read_b128 fragment loads.
// ---------------------------------------------------------------------------
__global__ __launch_bounds__(256, 2) void gemm_fused(
    const ushort_t* __restrict__ Ah, const ushort_t* __restrict__ Al,
    const ushort_t* __restrict__ Bh, const ushort_t* __restrict__ Bl,
    const float* __restrict__ bihf, const float* __restrict__ bhhf,
    const float* __restrict__ bihb, const float* __restrict__ bhhb,
    float* __restrict__ enc)
{
    __shared__ ushort_t As[8192];   // 128 x 64 bf16 (swizzled), 16 KB
    __shared__ ushort_t Bs[8192];
    const int tid = threadIdx.x;
    const int bx = blockIdx.x;
    const int bm = bx >> 2, q = bx & 3;
    const int dir = q >> 1, j0 = (q & 1)*128;
    const int row0 = bm*128;
    const float* __restrict__ bih = dir ? bihb : bihf;
    const float* __restrict__ bhh = dir ? bhhb : bhhf;
    const ushort_t* const Aseg[4] = {Ah, Al, Ah, Al};
    const ushort_t* const Bseg[4] = {Bh, Bh, Bl, Bl};

    const int lane = tid & 63, wv = tid >> 6;
    const int wm = wv >> 1, wn = wv & 1;
    const int lm = lane & 15, lq = lane >> 4;
    const int wbase = (tid & 192) * 8;        // wave-uniform LDS slot base (ushort idx)

    // staging address components (invariant): thread's slot -> (m, swizzled k8)
    const int smr = tid >> 3;                  // m within 32-row group
    const int k8x = (tid & 7) ^ (smr & 7);     // swizzled k8
    size_t aoff[4];
    #pragma unroll
    for (int g=0; g<4; ++g)
        aoff[g] = (size_t)(row0 + g*32 + smr)*HDIM + k8x*8;

    int jcol[4];
    #pragma unroll
    for (int fn=0; fn<4; ++fn) jcol[fn] = j0 + wn*64 + fn*16 + lm;

    float held[4][4][4];
    f32x4 acc[4][4];

    #pragma unroll 1
    for (int p=0; p<3; ++p){
        const int nbase = dir*768 + p*256 + j0;
        size_t boff[4];
        #pragma unroll
        for (int g=0; g<4; ++g)
            boff[g] = (size_t)(nbase + g*32 + smr)*HDIM + k8x*8;

        #pragma unroll
        for (int fm=0; fm<4; ++fm)
            #pragma unroll
            for (int fn=0; fn<4; ++fn)
                acc[fm][fn] = (f32x4){0.f,0.f,0.f,0.f};

        #pragma unroll 1
        for (int seg=0; seg<4; ++seg){
            const ushort_t* __restrict__ Ap = Aseg[seg];
            const ushort_t* __restrict__ Bp = Bseg[seg];
            #pragma unroll 1
            for (int kt=0; kt<12; ++kt){
                const int k0 = kt*64;
                #pragma unroll
                for (int g=0; g<4; ++g){
                    GLD16(Ap + aoff[g] + k0, &As[g*2048 + wbase]);
                    GLD16(Bp + boff[g] + k0, &Bs[g*2048 + wbase]);
                }
                __syncthreads();
                #pragma unroll
                for (int kc=0; kc<2; ++kc){
                    bf16x8 af[4], bf[4];
                    #pragma unroll
                    for (int f=0; f<4; ++f){
                        int m = wm*64 + f*16 + lm;
                        af[f] = *(const bf16x8*)&As[(m*8 + ((kc*4+lq) ^ (m&7)))*8];
                        int n = wn*64 + f*16 + lm;
                        bf[f] = *(const bf16x8*)&Bs[(n*8 + ((kc*4+lq) ^ (n&7)))*8];
                    }
                    #pragma unroll
                    for (int fm=0; fm<4; ++fm)
                        #pragma unroll
                        for (int fn=0; fn<4; ++fn)
                            acc[fm][fn] = __builtin_amdgcn_mfma_f32_16x16x32_bf16(
                                af[fm], bf[fn], acc[fm][fn], 0, 0, 0);
                }
                __syncthreads();
            }
        }

        // combine pass result
        const int gbase = (p==0) ? 0 : ((p==1) ? 512 : 768);
        float bias[4];
        #pragma unroll
        for (int fn=0; fn<4; ++fn)
            bias[fn] = bih[gbase + jcol[fn]] + bhh[gbase + jcol[fn]];

        if (p==0){
            #pragma unroll
            for (int fm=0; fm<4; ++fm)
                #pragma unroll
                for (int fn=0; fn<4; ++fn)
                    #pragma unroll
                    for (int r=0; r<4; ++r)
                        held[fm][fn][r] = sigm(acc[fm][fn][r] + bias[fn]);
        } else if (p==1){
            #pragma unroll
            for (int fm=0; fm<4; ++fm)
                #pragma unroll
                for (int fn=0; fn<4; ++fn)
                    #pragma unroll
                    for (int r=0; r<4; ++r)
                        held[fm][fn][r] *= tanhf(acc[fm][fn][r] + bias[fn]);
        } else {
            #pragma unroll
            for (int fm=0; fm<4; ++fm)
                #pragma unroll
                for (int fn=0; fn<4; ++fn)
                    #pragma unroll
                    for (int r=0; r<4; ++r){
                        float h = sigm(acc[fm][fn][r] + bias[fn]) * tanhf(held[fm][fn][r]);
                        int m = row0 + wm*64 + fm*16 + lq*4 + r;
                        int col = dir*256 + jcol[fn];
                        enc[(size_t)m*HIDD + col] = h;
                    }
        }
    }
}

// ---------------------------------------------------------------------------
// feats = enc @ w_tag.T + b_tag   (16384 x 20). 8 rows/block, 32 lanes/row.
// ---------------------------------------------------------------------------
__global__ __launch_bounds__(256) void feats_kernel(
    const float* __restrict__ enc, const float* __restrict__ wtag,
    const float* __restrict__ btag, float* __restrict__ feats)
{
    __shared__ float wt[NT*HIDD];
    const int tid = threadIdx.x;
    for (int idx=tid; idx<NT*HIDD/4; idx+=256)
        ((float4*)wt)[idx] = ((const float4*)wtag)[idx];
    __syncthreads();
    const int row = blockIdx.x*8 + (tid>>5);
    const int lane = tid & 31;
    float ev[16];
    #pragma unroll
    for (int m=0;m<16;++m) ev[m] = enc[(size_t)row*HIDD + lane + 32*m];
    for (int tag=0;tag<NT;++tag){
        float s = 0.f;
        #pragma unroll
        for (int m=0;m<16;++m) s = fmaf(ev[m], wt[tag*HIDD + lane + 32*m], s);
        #pragma unroll
        for (int off=16;off>=1;off>>=1) s += __shfl_xor(s, off, 32);
        if (lane==0) feats[(size_t)row*NT + tag] = s + btag[tag];
    }
}

// ---------------------------------------------------------------------------
// V1: per-chunk max-plus matrix product P_c (20x20). One block per chunk.
// ---------------------------------------------------------------------------
__global__ __launch_bounds__(512) void vit_chunkmat(
    const float* __restrict__ feats, const float* __restrict__ trans,
    float* __restrict__ Pall)
{
    __shared__ float fl[CLEN*NT];
    __shared__ float Pb[2][NT*NT];
    const int c = blockIdx.x, tid = threadIdx.x;
    for (int idx=tid; idx<CLEN*NT/4; idx+=512)
        ((float4*)fl)[idx] = ((const float4*)(feats + (size_t)c*CLEN*NT))[idx];
    const bool act = tid < NT*NT;
    const int i = tid/20, j = tid - i*20;
    float tr[NT];
    if (act){
        #pragma unroll
        for (int k=0;k<NT;++k) tr[k] = trans[i*NT+k];
        Pb[0][tid] = (i==j) ? 0.f : -1e30f;
    }
    __syncthreads();
    int cur = 0;
    for (int t=0;t<CLEN;++t){
        float m = -3.0e38f;
        if (act){
            #pragma unroll
            for (int k=0;k<NT;++k) m = fmaxf(m, tr[k] + Pb[cur][k*NT+j]);
            m += fl[t*NT+i];
            Pb[cur^1][tid] = m;
        }
        __syncthreads();
        cur ^= 1;
    }
    if (act) Pall[(size_t)c*(NT*NT) + tid] = Pb[cur][tid];
}

// ---------------------------------------------------------------------------
// V2: sequential chunk scan -> fv at chunk starts + terminal argmax/score.
// ---------------------------------------------------------------------------
__global__ __launch_bounds__(128) void vit_scan(
    const float* __restrict__ Pall, const float* __restrict__ trans,
    float* __restrict__ fvstart, float* __restrict__ dout, int* __restrict__ bestws)
{
    __shared__ float Pb[NT*NT];
    __shared__ float fv[NT];
    const int tid = threadIdx.x;
    float4 pn = {0.f,0.f,0.f,0.f};
    if (tid<100) pn = ((const float4*)Pall)[tid];
    if (tid<NT) fv[tid] = (tid==18) ? 0.f : -10000.f;
    for (int c=0;c<CHUNKS;++c){
        if (tid<100) ((float4*)Pb)[tid] = pn;
        if (tid<100 && c+1<CHUNKS) pn = ((const float4*)(Pall + (size_t)(c+1)*(NT*NT)))[tid];
        __syncthreads();
        if (tid<NT) fvstart[c*NT+tid] = fv[tid];
        float nf = -3.0e38f;
        if (tid<NT){
            #pragma unroll
            for (int j=0;j<NT;++j) nf = fmaxf(nf, Pb[tid*NT+j] + fv[j]);
        }
        __syncthreads();
        if (tid<NT) fv[tid] = nf;
    }
    __syncthreads();
    if (tid==0){
        float best = -3.0e38f; int bidx = 0;
        for (int j=0;j<NT;++j){
            float tv = fv[j] + trans[19*NT+j];
            if (tv > best){ best = tv; bidx = j; }
        }
        dout[0] = best;
        bestws[0] = bidx;
    }
}

// ---------------------------------------------------------------------------
// V3: exact per-step replay (reference argmax semantics) -> backpointers + H_c
// ---------------------------------------------------------------------------
__global__ __launch_bounds__(64) void vit_replay(
    const float* __restrict__ feats, const float* __restrict__ trans,
    const float* __restrict__ fvstart, unsigned int* __restrict__ bpout,
    int* __restrict__ Hout)
{
    __shared__ float fl[CLEN*NT];
    __shared__ float fv[NT];
    __shared__ unsigned char bp[CLEN*NT];
    const int c = blockIdx.x, tid = threadIdx.x;
    for (int idx=tid; idx<CLEN*NT/4; idx+=64)
        ((float4*)fl)[idx] = ((const float4*)(feats + (size_t)c*CLEN*NT))[idx];
    float tr[NT];
    if (tid<NT){
        fv[tid] = fvstart[c*NT+tid];
        #pragma unroll
        for (int k=0;k<NT;++k) tr[k] = trans[tid*NT+k];
    }
    __syncthreads();
    for (int t=0;t<CLEN;++t){
        float best = 0.f; int bj = 0;
        if (tid<NT){
            best = tr[0] + fv[0];
            #pragma unroll
            for (int j=1;j<NT;++j){
                float v = tr[j] + fv[j];
                if (v > best){ best = v; bj = j; }
            }
        }
        __syncthreads();
        if (tid<NT){
            fv[tid] = best + fl[t*NT+tid];
            bp[t*NT+tid] = (unsigned char)bj;
        }
        __syncthreads();
    }
    for (int idx=tid; idx<CLEN*NT/4; idx+=64)
        bpout[(size_t)c*(CLEN*NT/4) + idx] = ((unsigned int*)bp)[idx];
    if (tid<NT){
        int m = tid;
        for (int t=CLEN-1;t>=0;--t) m = bp[t*NT+m];
        Hout[c*NT+tid] = m;
    }
}

// ---------------------------------------------------------------------------
__global__ __launch_bounds__(64) void bt_scan(
    const int* __restrict__ Hin, const int* __restrict__ bestws,
    int* __restrict__ echunk)
{
    __shared__ int Hl[CHUNKS*NT];
    const int tid = threadIdx.x;
    for (int idx=tid; idx<CHUNKS*NT; idx+=64) Hl[idx] = Hin[idx];
    __syncthreads();
    if (tid==0){
        int e = bestws[0];
        echunk[CHUNKS-1] = e;
        for (int c=CHUNKS-1;c>=1;--c){ e = Hl[c*NT+e]; echunk[c-1] = e; }
    }
}

// ---------------------------------------------------------------------------
__global__ __launch_bounds__(64) void bt_fill(
    const unsigned int* __restrict__ bpin, const int* __restrict__ echunk,
    float* __restrict__ dout)
{
    __shared__ unsigned char bp[CLEN*NT];
    __shared__ float ob[CLEN];
    const int c = blockIdx.x, tid = threadIdx.x;
    for (int idx=tid; idx<CLEN*NT/4; idx+=64)
        ((unsigned int*)bp)[idx] = bpin[(size_t)c*(CLEN*NT/4) + idx];
    __syncthreads();
    if (tid==0){
        int y = echunk[c];
        for (int t=CLEN-1;t>=0;--t){ ob[t] = (float)y; y = bp[t*NT+y]; }
    }
    __syncthreads();
    for (int idx=tid; idx<CLEN; idx+=64)
        dout[1 + c*CLEN + idx] = ob[idx];
}

// ---------------------------------------------------------------------------
extern "C" void kernel_launch(void* const* d_in, const int* in_sizes, int n_in,
                              void* d_out, int out_size, void* d_ws, size_t ws_size,
                              hipStream_t stream)
{
    const float* x    = (const float*)d_in[0];
    const float* wf   = (const float*)d_in[1];
    const float* bihf = (const float*)d_in[3];
    const float* bhhf = (const float*)d_in[4];
    const float* wb   = (const float*)d_in[5];
    const float* bihb = (const float*)d_in[7];
    const float* bhhb = (const float*)d_in[8];
    const float* wtag = (const float*)d_in[9];
    const float* btag = (const float*)d_in[10];
    const float* trans= (const float*)d_in[11];
    float* out = (float*)d_out;

    char* w = (char*)d_ws;
    ushort_t* Ah = (ushort_t*)w;        w += 25165824;   // 16384*768*2
    ushort_t* Al = (ushort_t*)w;        w += 25165824;
    ushort_t* Bh = (ushort_t*)w;        w += 2359296;    // 1536*768*2
    ushort_t* Bl = (ushort_t*)w;        w += 2359296;
    float* enc   = (float*)w;           w += 33554432;   // 16384*512*4
    float* feats = (float*)w;           w += 1310720;    // 16384*20*4
    float* Pall  = (float*)w;           w += 204800;     // 128*400*4
    float* fvst  = (float*)w;           w += 10240;      // 128*20*4
    int* Hmap    = (int*)w;             w += 10240;      // 128*20*4
    unsigned int* bp = (unsigned int*)w; w += 327680;    // 16384*20 bytes
    int* ech     = (int*)w;             w += 512;
    int* best    = (int*)w;

    convB_kernel<<<1152, 256, 0, stream>>>(wf, wb, Bh, Bl);
    convA_kernel<<<12288, 256, 0, stream>>>(x, Ah, Al);
    gemm_fused<<<512, 256, 0, stream>>>(Ah, Al, Bh, Bl, bihf, bhhf, bihb, bhhb, enc);
    feats_kernel<<<2048, 256, 0, stream>>>(enc, wtag, btag, feats);
    vit_chunkmat<<<CHUNKS, 512, 0, stream>>>(feats, trans, Pall);
    vit_scan<<<1, 128, 0, stream>>>(Pall, trans, fvst, out, best);
    vit_replay<<<CHUNKS, 64, 0, stream>>>(feats, trans, fvst, bp, Hmap);
    bt_scan<<<1, 64, 0, stream>>>(Hmap, best, ech);
    bt_fill<<<CHUNKS, 64, 0, stream>>>(bp, ech, out);
}

// Round 3
// 440.278 us; speedup vs baseline: 1.5927x; 1.1501x over previous
//
#include <hip/hip_runtime.h>
#include <math.h>

#define HDIM 768
#define HIDD 512
#define NTOK 16384
#define NT 20
#define CHUNKS 128
#define CLEN 128

typedef unsigned short ushort_t;
typedef __attribute__((ext_vector_type(8))) short bf16x8;
typedef __attribute__((ext_vector_type(4))) float f32x4;

__device__ __forceinline__ float sigm(float x){ return 1.0f/(1.0f+expf(-x)); }

__device__ __forceinline__ ushort_t f2bf(float f){
    unsigned int u = __float_as_uint(f);
    unsigned int r = (u + 0x7fffu + ((u >> 16) & 1u)) >> 16;
    return (ushort_t)r;
}
__device__ __forceinline__ float bf2f(ushort_t b){
    return __uint_as_float(((unsigned int)b) << 16);
}

#define GLD16(gp, lp) __builtin_amdgcn_global_load_lds( \
    (const __attribute__((address_space(1))) void*)(gp), \
    (__attribute__((address_space(3))) void*)(lp), 16, 0, 0)

// ---------------------------------------------------------------------------
// Fused conversion kernel: blocks [0,1152) pack B (w_ih f/b gates i,g,o),
// blocks [1152, 13440) split x rows 1..16384 into bf16 hi/lo.
// ---------------------------------------------------------------------------
__global__ __launch_bounds__(256) void conv_kernel(
    const float* __restrict__ x,
    const float* __restrict__ wf, const float* __restrict__ wb,
    ushort_t* __restrict__ Ah, ushort_t* __restrict__ Al,
    ushort_t* __restrict__ Bh, ushort_t* __restrict__ Bl)
{
    const int bid = blockIdx.x;
    if (bid < 1152){
        int t = bid*256 + threadIdx.x;                 // 1536*192
        int n = t / 192, c4 = (t - n*192)*4;
        int dir = n / 768, nr = n - dir*768;
        int gate = nr >> 8, j = nr & 255;
        int wrow = j + ((gate==0)?0:((gate==1)?512:768));
        const float* src = dir ? wb : wf;
        const float4 v = *(const float4*)(src + (size_t)wrow*HDIM + c4);
        float f[4] = {v.x, v.y, v.z, v.w};
        ushort_t h[4], l[4];
        #pragma unroll
        for (int i=0;i<4;++i){
            h[i] = f2bf(f[i]);
            l[i] = f2bf(f[i] - bf2f(h[i]));
        }
        *(ushort4*)(Bh + (size_t)n*HDIM + c4) = make_ushort4(h[0],h[1],h[2],h[3]);
        *(ushort4*)(Bl + (size_t)n*HDIM + c4) = make_ushort4(l[0],l[1],l[2],l[3]);
    } else {
        int t = (bid-1152)*256 + threadIdx.x;          // 16384*192
        int row = t / 192, c4 = (t - row*192)*4;
        const float4 v = *(const float4*)(x + (size_t)(row+1)*HDIM + c4);
        float f[4] = {v.x, v.y, v.z, v.w};
        ushort_t h[4], l[4];
        #pragma unroll
        for (int i=0;i<4;++i){
            h[i] = f2bf(f[i]);
            l[i] = f2bf(f[i] - bf2f(h[i]));
        }
        *(ushort4*)(Ah + (size_t)row*HDIM + c4) = make_ushort4(h[0],h[1],h[2],h[3]);
        *(ushort4*)(Al + (size_t)row*HDIM + c4) = make_ushort4(l[0],l[1],l[2],l[3]);
    }
}

// ---------------------------------------------------------------------------
// Fused split-bf16 MFMA GEMM + gates + partial-feats epilogue.
// Per block: 128 m-rows x (dir, j-half 128). 3 gate passes; each pass one
// K-loop with Ah/Al/Bh/Bl tiles co-resident, 3 products (hh, lh, hl; ll
// dropped: ~2^-16 relative). Epilogue computes h then partial
// feats_q[m][tag] = h_tile(128x128) . wtag_slice^T, written to per-q buffer
// (deterministic sum later; no atomics). enc is never materialized.
// ---------------------------------------------------------------------------
__global__ __launch_bounds__(256, 2) void gemm_fused(
    const ushort_t* __restrict__ Ah, const ushort_t* __restrict__ Al,
    const ushort_t* __restrict__ Bh, const ushort_t* __restrict__ Bl,
    const float* __restrict__ bihf, const float* __restrict__ bhhf,
    const float* __restrict__ bihb, const float* __restrict__ bhhb,
    const float* __restrict__ wtag, float* __restrict__ featsp)
{
    __shared__ __align__(16) char smem[65536];
    ushort_t* As_h = (ushort_t*)smem;              // 128x64 bf16 swizzled
    ushort_t* As_l = (ushort_t*)(smem + 16384);
    ushort_t* Bs_h = (ushort_t*)(smem + 32768);
    ushort_t* Bs_l = (ushort_t*)(smem + 49152);
    float* hbuf = (float*)smem;                    // epilogue: 64x129 f32
    float* wts  = (float*)(smem + 33024);          // epilogue: 20x128 f32

    const int tid = threadIdx.x;
    const int bx = blockIdx.x;
    const int bm = bx >> 2, q = bx & 3;
    const int dir = q >> 1, j0 = (q & 1)*128;
    const int row0 = bm*128;
    const float* __restrict__ bih = dir ? bihb : bihf;
    const float* __restrict__ bhh = dir ? bhhb : bhhf;

    const int lane = tid & 63, wv = tid >> 6;
    const int wm = wv >> 1, wn = wv & 1;
    const int lm = lane & 15, lq = lane >> 4;
    const int wbase = (tid & 192) * 8;             // wave-uniform LDS slot base

    const int smr = tid >> 3;                      // m within 32-row group
    const int k8x = (tid & 7) ^ (smr & 7);         // swizzled k8
    size_t aoff[4];
    #pragma unroll
    for (int g=0; g<4; ++g)
        aoff[g] = (size_t)(row0 + g*32 + smr)*HDIM + k8x*8;

    int jcol[4];
    #pragma unroll
    for (int fn=0; fn<4; ++fn) jcol[fn] = j0 + wn*64 + fn*16 + lm;

    float held[4][4][4];
    f32x4 acc[4][4];

    #pragma unroll 1
    for (int p=0; p<3; ++p){
        const int nbase = dir*768 + p*256 + j0;
        size_t boff[4];
        #pragma unroll
        for (int g=0; g<4; ++g)
            boff[g] = (size_t)(nbase + g*32 + smr)*HDIM + k8x*8;

        #pragma unroll
        for (int fm=0; fm<4; ++fm)
            #pragma unroll
            for (int fn=0; fn<4; ++fn)
                acc[fm][fn] = (f32x4){0.f,0.f,0.f,0.f};

        #pragma unroll 1
        for (int kt=0; kt<12; ++kt){
            const int k0 = kt*64;
            #pragma unroll
            for (int g=0; g<4; ++g){
                GLD16(Ah + aoff[g] + k0, &As_h[g*2048 + wbase]);
                GLD16(Al + aoff[g] + k0, &As_l[g*2048 + wbase]);
                GLD16(Bh + boff[g] + k0, &Bs_h[g*2048 + wbase]);
                GLD16(Bl + boff[g] + k0, &Bs_l[g*2048 + wbase]);
            }
            __syncthreads();
            #pragma unroll
            for (int kc=0; kc<2; ++kc){
                bf16x8 afh[4], afl[4], bfh[4], bfl[4];
                #pragma unroll
                for (int f=0; f<4; ++f){
                    int m = wm*64 + f*16 + lm;
                    int sa = (m*8 + ((kc*4+lq) ^ (m&7)))*8;
                    afh[f] = *(const bf16x8*)&As_h[sa];
                    afl[f] = *(const bf16x8*)&As_l[sa];
                    int n = wn*64 + f*16 + lm;
                    int sb = (n*8 + ((kc*4+lq) ^ (n&7)))*8;
                    bfh[f] = *(const bf16x8*)&Bs_h[sb];
                    bfl[f] = *(const bf16x8*)&Bs_l[sb];
                }
                #pragma unroll
                for (int fm=0; fm<4; ++fm)
                    #pragma unroll
                    for (int fn=0; fn<4; ++fn){
                        acc[fm][fn] = __builtin_amdgcn_mfma_f32_16x16x32_bf16(
                            afh[fm], bfh[fn], acc[fm][fn], 0, 0, 0);
                        acc[fm][fn] = __builtin_amdgcn_mfma_f32_16x16x32_bf16(
                            afl[fm], bfh[fn], acc[fm][fn], 0, 0, 0);
                        acc[fm][fn] = __builtin_amdgcn_mfma_f32_16x16x32_bf16(
                            afh[fm], bfl[fn], acc[fm][fn], 0, 0, 0);
                    }
            }
            __syncthreads();
        }

        const int gbase = (p==0) ? 0 : ((p==1) ? 512 : 768);
        float bias[4];
        #pragma unroll
        for (int fn=0; fn<4; ++fn)
            bias[fn] = bih[gbase + jcol[fn]] + bhh[gbase + jcol[fn]];

        if (p==0){
            #pragma unroll
            for (int fm=0; fm<4; ++fm)
                #pragma unroll
                for (int fn=0; fn<4; ++fn)
                    #pragma unroll
                    for (int r=0; r<4; ++r)
                        held[fm][fn][r] = sigm(acc[fm][fn][r] + bias[fn]);
        } else if (p==1){
            #pragma unroll
            for (int fm=0; fm<4; ++fm)
                #pragma unroll
                for (int fn=0; fn<4; ++fn)
                    #pragma unroll
                    for (int r=0; r<4; ++r)
                        held[fm][fn][r] *= tanhf(acc[fm][fn][r] + bias[fn]);
        } else {
            // h values for this thread's 64 fragment elements
            float hv[4][4][4];
            #pragma unroll
            for (int fm=0; fm<4; ++fm)
                #pragma unroll
                for (int fn=0; fn<4; ++fn)
                    #pragma unroll
                    for (int r=0; r<4; ++r)
                        hv[fm][fn][r] = sigm(acc[fm][fn][r] + bias[fn]) * tanhf(held[fm][fn][r]);

            // wtag slice for this block's 128 j-cols (tiles are dead: last
            // K-loop iteration ended with __syncthreads)
            for (int idx=tid; idx<NT*128; idx+=256){
                int t = idx >> 7, j = idx & 127;
                wts[idx] = wtag[t*HIDD + dir*256 + j0 + j];
            }
            float* fq = featsp + (size_t)q * (NTOK*NT);
            #pragma unroll 1
            for (int ph=0; ph<2; ++ph){
                __syncthreads();
                if (wm == ph){
                    #pragma unroll
                    for (int fm=0; fm<4; ++fm)
                        #pragma unroll
                        for (int fn=0; fn<4; ++fn)
                            #pragma unroll
                            for (int r=0; r<4; ++r){
                                int mloc = fm*16 + lq*4 + r;         // 0..63
                                int jloc = wn*64 + fn*16 + lm;       // 0..127
                                hbuf[mloc*129 + jloc] = hv[fm][fn][r];
                            }
                }
                __syncthreads();
                const int mrow = tid & 63, tg0 = (tid >> 6) * 5;
                float s[5] = {0.f,0.f,0.f,0.f,0.f};
                for (int j=0;j<128;++j){
                    float h = hbuf[mrow*129 + j];
                    #pragma unroll
                    for (int tt=0; tt<5; ++tt)
                        s[tt] = fmaf(h, wts[(tg0+tt)*128 + j], s[tt]);
                }
                const int mglob = row0 + ph*64 + mrow;
                #pragma unroll
                for (int tt=0; tt<5; ++tt)
                    fq[(size_t)mglob*NT + tg0 + tt] = s[tt];
            }
        }
    }
}

// ---------------------------------------------------------------------------
// fl loader shared by chunkmat/replay: identical deterministic sum of the 4
// partial buffers + btag (no atomics -> bit-identical across both kernels).
// ---------------------------------------------------------------------------
__device__ __forceinline__ void load_fl(
    const float* __restrict__ featsp, const float* __restrict__ btg,
    float* fl, int c, int tid, int nthr)
{
    const float4* p0 = (const float4*)(featsp);
    const float4* p1 = (const float4*)(featsp + (size_t)NTOK*NT);
    const float4* p2 = (const float4*)(featsp + (size_t)2*NTOK*NT);
    const float4* p3 = (const float4*)(featsp + (size_t)3*NTOK*NT);
    const int base = c*(CLEN*NT/4);
    for (int idx=tid; idx<CLEN*NT/4; idx+=nthr){
        float4 a = p0[base+idx], b = p1[base+idx];
        float4 d = p2[base+idx], e = p3[base+idx];
        float4 v;
        v.x = (a.x+b.x)+(d.x+e.x);
        v.y = (a.y+b.y)+(d.y+e.y);
        v.z = (a.z+b.z)+(d.z+e.z);
        v.w = (a.w+b.w)+(d.w+e.w);
        int t0 = (idx*4) % 20;                 // components never wrap past 20
        v.x += btg[t0]; v.y += btg[t0+1]; v.z += btg[t0+2]; v.w += btg[t0+3];
        ((float4*)fl)[idx] = v;
    }
}

// ---------------------------------------------------------------------------
// V1: per-chunk max-plus matrix product P_c (20x20). One block per chunk.
// ---------------------------------------------------------------------------
__global__ __launch_bounds__(512) void vit_chunkmat(
    const float* __restrict__ featsp, const float* __restrict__ btag,
    const float* __restrict__ trans, float* __restrict__ Pall)
{
    __shared__ float fl[CLEN*NT];
    __shared__ float Pb[2][NT*NT];
    const int c = blockIdx.x, tid = threadIdx.x;
    load_fl(featsp, btag, fl, c, tid, 512);
    const bool act = tid < NT*NT;
    const int i = tid/20, j = tid - i*20;
    float tr[NT];
    if (act){
        #pragma unroll
        for (int k=0;k<NT;++k) tr[k] = trans[i*NT+k];
        Pb[0][tid] = (i==j) ? 0.f : -1e30f;
    }
    __syncthreads();
    int cur = 0;
    for (int t=0;t<CLEN;++t){
        float m = -3.0e38f;
        if (act){
            #pragma unroll
            for (int k=0;k<NT;++k) m = fmaxf(m, tr[k] + Pb[cur][k*NT+j]);
            m += fl[t*NT+i];
            Pb[cur^1][tid] = m;
        }
        __syncthreads();
        cur ^= 1;
    }
    if (act) Pall[(size_t)c*(NT*NT) + tid] = Pb[cur][tid];
}

// ---------------------------------------------------------------------------
// V2: sequential chunk scan -> fv at chunk starts + terminal argmax/score.
// ---------------------------------------------------------------------------
__global__ __launch_bounds__(128) void vit_scan(
    const float* __restrict__ Pall, const float* __restrict__ trans,
    float* __restrict__ fvstart, float* __restrict__ dout, int* __restrict__ bestws)
{
    __shared__ float Pb[NT*NT];
    __shared__ float fv[NT];
    const int tid = threadIdx.x;
    float4 pn = {0.f,0.f,0.f,0.f};
    if (tid<100) pn = ((const float4*)Pall)[tid];
    if (tid<NT) fv[tid] = (tid==18) ? 0.f : -10000.f;
    for (int c=0;c<CHUNKS;++c){
        if (tid<100) ((float4*)Pb)[tid] = pn;
        if (tid<100 && c+1<CHUNKS) pn = ((const float4*)(Pall + (size_t)(c+1)*(NT*NT)))[tid];
        __syncthreads();
        if (tid<NT) fvstart[c*NT+tid] = fv[tid];
        float nf = -3.0e38f;
        if (tid<NT){
            #pragma unroll
            for (int j=0;j<NT;++j) nf = fmaxf(nf, Pb[tid*NT+j] + fv[j]);
        }
        __syncthreads();
        if (tid<NT) fv[tid] = nf;
    }
    __syncthreads();
    if (tid==0){
        float best = -3.0e38f; int bidx = 0;
        for (int j=0;j<NT;++j){
            float tv = fv[j] + trans[19*NT+j];
            if (tv > best){ best = tv; bidx = j; }
        }
        dout[0] = best;
        bestws[0] = bidx;
    }
}

// ---------------------------------------------------------------------------
// V3: exact per-step replay (reference argmax semantics) -> backpointers + H_c
// ---------------------------------------------------------------------------
__global__ __launch_bounds__(64) void vit_replay(
    const float* __restrict__ featsp, const float* __restrict__ btag,
    const float* __restrict__ trans, const float* __restrict__ fvstart,
    unsigned int* __restrict__ bpout, int* __restrict__ Hout)
{
    __shared__ float fl[CLEN*NT];
    __shared__ float fv[NT];
    __shared__ unsigned char bp[CLEN*NT];
    const int c = blockIdx.x, tid = threadIdx.x;
    load_fl(featsp, btag, fl, c, tid, 64);
    float tr[NT];
    if (tid<NT){
        fv[tid] = fvstart[c*NT+tid];
        #pragma unroll
        for (int k=0;k<NT;++k) tr[k] = trans[tid*NT+k];
    }
    __syncthreads();
    for (int t=0;t<CLEN;++t){
        float best = 0.f; int bj = 0;
        if (tid<NT){
            best = tr[0] + fv[0];
            #pragma unroll
            for (int j=1;j<NT;++j){
                float v = tr[j] + fv[j];
                if (v > best){ best = v; bj = j; }
            }
        }
        __syncthreads();
        if (tid<NT){
            fv[tid] = best + fl[t*NT+tid];
            bp[t*NT+tid] = (unsigned char)bj;
        }
        __syncthreads();
    }
    for (int idx=tid; idx<CLEN*NT/4; idx+=64)
        bpout[(size_t)c*(CLEN*NT/4) + idx] = ((unsigned int*)bp)[idx];
    if (tid<NT){
        int m = tid;
        for (int t=CLEN-1;t>=0;--t) m = bp[t*NT+m];
        Hout[c*NT+tid] = m;
    }
}

// ---------------------------------------------------------------------------
// V4 (fused): each block walks the composed chunk maps from bestws down to
// its own chunk, then backtracks its chunk and writes the path slice.
// ---------------------------------------------------------------------------
__global__ __launch_bounds__(64) void bt_fill(
    const unsigned int* __restrict__ bpin, const int* __restrict__ Hin,
    const int* __restrict__ bestws, float* __restrict__ dout)
{
    __shared__ int Hl[CHUNKS*NT];
    __shared__ unsigned char bp[CLEN*NT];
    __shared__ float ob[CLEN];
    const int c = blockIdx.x, tid = threadIdx.x;
    for (int idx=tid; idx<CHUNKS*NT; idx+=64) Hl[idx] = Hin[idx];
    for (int idx=tid; idx<CLEN*NT/4; idx+=64)
        ((unsigned int*)bp)[idx] = bpin[(size_t)c*(CLEN*NT/4) + idx];
    __syncthreads();
    if (tid==0){
        int e = bestws[0];
        for (int cc=CHUNKS-1; cc>c; --cc) e = Hl[cc*NT+e];
        for (int t=CLEN-1;t>=0;--t){ ob[t] = (float)e; e = bp[t*NT+e]; }
    }
    __syncthreads();
    for (int idx=tid; idx<CLEN; idx+=64)
        dout[1 + c*CLEN + idx] = ob[idx];
}

// ---------------------------------------------------------------------------
extern "C" void kernel_launch(void* const* d_in, const int* in_sizes, int n_in,
                              void* d_out, int out_size, void* d_ws, size_t ws_size,
                              hipStream_t stream)
{
    const float* x    = (const float*)d_in[0];
    const float* wf   = (const float*)d_in[1];
    const float* bihf = (const float*)d_in[3];
    const float* bhhf = (const float*)d_in[4];
    const float* wb   = (const float*)d_in[5];
    const float* bihb = (const float*)d_in[7];
    const float* bhhb = (const float*)d_in[8];
    const float* wtag = (const float*)d_in[9];
    const float* btag = (const float*)d_in[10];
    const float* trans= (const float*)d_in[11];
    float* out = (float*)d_out;

    char* w = (char*)d_ws;
    ushort_t* Ah = (ushort_t*)w;         w += 25165824;   // 16384*768*2
    ushort_t* Al = (ushort_t*)w;         w += 25165824;
    ushort_t* Bh = (ushort_t*)w;         w += 2359296;    // 1536*768*2
    ushort_t* Bl = (ushort_t*)w;         w += 2359296;
    float* featsp = (float*)w;           w += 5242880;    // 4 * 16384*20 * 4B
    float* Pall  = (float*)w;            w += 204800;     // 128*400*4
    float* fvst  = (float*)w;            w += 10240;      // 128*20*4
    int* Hmap    = (int*)w;              w += 10240;      // 128*20*4
    unsigned int* bp = (unsigned int*)w; w += 327680;     // 16384*20 bytes
    int* best    = (int*)w;

    conv_kernel<<<13440, 256, 0, stream>>>(x, wf, wb, Ah, Al, Bh, Bl);
    gemm_fused<<<512, 256, 0, stream>>>(Ah, Al, Bh, Bl, bihf, bhhf, bihb, bhhb,
                                        wtag, featsp);
    vit_chunkmat<<<CHUNKS, 512, 0, stream>>>(featsp, btag, trans, Pall);
    vit_scan<<<1, 128, 0, stream>>>(Pall, trans, fvst, out, best);
    vit_replay<<<CHUNKS, 64, 0, stream>>>(featsp, btag, trans, fvst, bp, Hmap);
    bt_fill<<<CHUNKS, 64, 0, stream>>>(bp, Hmap, best, out);
}